// Round 1
// baseline (1651.391 us; speedup 1.0000x reference)
//
#include <hip/hip_runtime.h>

#define DEVFN static __device__ __forceinline__

typedef __bf16 bf16;
typedef __bf16 bf16x8 __attribute__((ext_vector_type(8)));
typedef __bf16 bf16x4 __attribute__((ext_vector_type(4)));
typedef float f32x4 __attribute__((ext_vector_type(4)));
typedef short short8 __attribute__((ext_vector_type(8)));

constexpr int Bc = 4, Hn = 16, Sn = 2048, DH = 128, Dn = 2048;
constexpr long MROWS = (long)Bc * Sn;  // 8192

// ---------- MFMA wrapper: dual-signature dispatch (V8y preferred, V8s fallback) ----------
template <typename T, typename C>
DEVFN auto mfma_impl(T a, T b, C c, int)
    -> decltype(__builtin_amdgcn_mfma_f32_16x16x32_bf16(a, b, c, 0, 0, 0)) {
  return __builtin_amdgcn_mfma_f32_16x16x32_bf16(a, b, c, 0, 0, 0);
}
template <typename T, typename C>
DEVFN C mfma_impl(T a, T b, C c, long) {
  return __builtin_amdgcn_mfma_f32_16x16x32_bf16(
      __builtin_bit_cast(short8, a), __builtin_bit_cast(short8, b), c, 0, 0, 0);
}
DEVFN f32x4 MFMA(bf16x8 a, bf16x8 b, f32x4 c) { return mfma_impl(a, b, c, 0); }

// ---------- async global->LDS 16B ----------
DEVFN void gld_lds16(const bf16* g, bf16* s) {
  __builtin_amdgcn_global_load_lds(
      (const __attribute__((address_space(1))) unsigned int*)g,
      (__attribute__((address_space(3))) unsigned int*)s, 16, 0, 0);
}

// Stage a 128x64 bf16 tile (row stride ld elems) into LDS, linear dest,
// source pre-swizzled so that reads with byte^((row&7)<<4) are conflict-free.
DEVFN void stage_tile(const bf16* __restrict__ g, long ld, bf16* __restrict__ s) {
  const int t = threadIdx.x;
  const int rr = t >> 3;
  const int cb = (t & 7) * 16;  // byte offset within 128B row
#pragma unroll
  for (int ch = 0; ch < 4; ++ch) {
    const int r = ch * 32 + rr;
    const int scb = cb ^ ((r & 7) << 4);
    gld_lds16(g + (long)r * ld + (scb >> 1), s + r * 64 + (cb >> 1));
  }
}

// Swizzled fragment read: 8 contiguous bf16 at (tile-local row, k element)
DEVFN bf16x8 ldfrag(const bf16* s, int row, int kelem) {
  const int cb = (kelem * 2) ^ ((row & 7) << 4);
  return *(const bf16x8*)(s + row * 64 + (cb >> 1));
}

// ---------- split / convert ----------
__global__ __launch_bounds__(256) void k_split(const float* __restrict__ x,
                                               bf16* __restrict__ hi,
                                               bf16* __restrict__ lo, long n) {
  long i = ((long)blockIdx.x * blockDim.x + threadIdx.x) * 4;
  if (i >= n) return;
  float4 v = *(const float4*)(x + i);
  float a[4] = {v.x, v.y, v.z, v.w};
  bf16x4 h, l;
#pragma unroll
  for (int t = 0; t < 4; ++t) {
    bf16 hb = (bf16)a[t];
    h[t] = hb;
    l[t] = (bf16)(a[t] - (float)hb);
  }
  *(bf16x4*)(hi + i) = h;
  *(bf16x4*)(lo + i) = l;
}

__global__ __launch_bounds__(256) void k_cvt(const float* __restrict__ x,
                                             bf16* __restrict__ y, long n) {
  long i = ((long)blockIdx.x * blockDim.x + threadIdx.x) * 4;
  if (i >= n) return;
  float4 v = *(const float4*)(x + i);
  bf16x4 h;
  h[0] = (bf16)v.x; h[1] = (bf16)v.y; h[2] = (bf16)v.z; h[3] = (bf16)v.w;
  *(bf16x4*)(y + i) = h;
}

// ---------- generic C = A @ B^T  (both operands row-major, K contiguous) ----------
// PASSES: 1 = plain bf16, 3 = split-bf16 (hi*hi + hi*lo + lo*hi)
// OUTMODE: 0 = split bf16 pair, 1 = bf16, 2 = f32 + bias, 3 = f32
// CAUSAL: per-(b,h) QK^T, skip tiles above diagonal
template <int PASSES, int OUTMODE, bool CAUSAL>
__global__ __launch_bounds__(256) void k_gemm_bt(
    const bf16* __restrict__ Ahi, const bf16* __restrict__ Alo, long ldA,
    const bf16* __restrict__ Bhi, const bf16* __restrict__ Blo, long ldB, int K,
    bf16* __restrict__ obh, bf16* __restrict__ obl, float* __restrict__ of,
    const float* __restrict__ bias, long ldC) {
  const int nt = blockIdx.x, mt = blockIdx.y;
  long aBase = 0, bBase = 0, cBase = 0;
  if constexpr (CAUSAL) {
    if (nt > mt) return;
    const int bhz = blockIdx.z, b = bhz >> 4, h = bhz & 15;
    aBase = (long)b * Sn * ldA + h * DH;
    bBase = (long)b * Sn * ldB + h * DH;
    cBase = (long)bhz * Sn * Sn;
  }
  constexpr int NT = (PASSES == 3) ? 2 : 1;
  __shared__ __align__(16) bf16 sA[NT][128 * 64];
  __shared__ __align__(16) bf16 sB[NT][128 * 64];
  const int tid = threadIdx.x, w = tid >> 6, lane = tid & 63;
  const int wm = (w >> 1) * 64, wn = (w & 1) * 64;
  const int lr = lane & 15, lg = lane >> 4;
  f32x4 acc[4][4] = {};
  const bf16* Ab = Ahi + aBase + (long)mt * 128 * ldA;
  const bf16* Bb = Bhi + bBase + (long)nt * 128 * ldB;
  const bf16* AbL = (PASSES == 3) ? (Alo + aBase + (long)mt * 128 * ldA) : nullptr;
  const bf16* BbL = (PASSES == 3) ? (Blo + bBase + (long)nt * 128 * ldB) : nullptr;

  for (int kt = 0; kt < K; kt += 64) {
    stage_tile(Ab + kt, ldA, sA[0]);
    stage_tile(Bb + kt, ldB, sB[0]);
    if constexpr (PASSES == 3) {
      stage_tile(AbL + kt, ldA, sA[1]);
      stage_tile(BbL + kt, ldB, sB[1]);
    }
    __syncthreads();
#pragma unroll
    for (int kk = 0; kk < 64; kk += 32) {
      bf16x8 ahf[4], bhf[4], alf[4], blf[4];
#pragma unroll
      for (int m = 0; m < 4; ++m) ahf[m] = ldfrag(sA[0], wm + m * 16 + lr, kk + lg * 8);
#pragma unroll
      for (int n = 0; n < 4; ++n) bhf[n] = ldfrag(sB[0], wn + n * 16 + lr, kk + lg * 8);
      if constexpr (PASSES == 3) {
#pragma unroll
        for (int m = 0; m < 4; ++m) alf[m] = ldfrag(sA[1], wm + m * 16 + lr, kk + lg * 8);
#pragma unroll
        for (int n = 0; n < 4; ++n) blf[n] = ldfrag(sB[1], wn + n * 16 + lr, kk + lg * 8);
      }
#pragma unroll
      for (int m = 0; m < 4; ++m)
#pragma unroll
        for (int n = 0; n < 4; ++n) {
          acc[m][n] = MFMA(ahf[m], bhf[n], acc[m][n]);
          if constexpr (PASSES == 3) {
            acc[m][n] = MFMA(ahf[m], blf[n], acc[m][n]);
            acc[m][n] = MFMA(alf[m], bhf[n], acc[m][n]);
          }
        }
    }
    __syncthreads();
  }

#pragma unroll
  for (int m = 0; m < 4; ++m)
#pragma unroll
    for (int n = 0; n < 4; ++n) {
      const int col = nt * 128 + wn + n * 16 + lr;
#pragma unroll
      for (int r = 0; r < 4; ++r) {
        const long row = (long)mt * 128 + wm + m * 16 + lg * 4 + r;
        const float cv = acc[m][n][r];
        const long idx = cBase + row * ldC + col;
        if constexpr (OUTMODE == 0) {
          bf16 hv = (bf16)cv;
          obh[idx] = hv;
          obl[idx] = (bf16)(cv - (float)hv);
        } else if constexpr (OUTMODE == 1) {
          obh[idx] = (bf16)cv;
        } else if constexpr (OUTMODE == 2) {
          of[idx] = cv + bias[col];
        } else {
          of[idx] = cv;
        }
      }
    }
}

// ---------- in-place causal row softmax on fp32 weights ----------
DEVFN float wred_max(float x) {
#pragma unroll
  for (int o = 32; o > 0; o >>= 1) x = fmaxf(x, __shfl_xor(x, o, 64));
  return x;
}
DEVFN float wred_sum(float x) {
#pragma unroll
  for (int o = 32; o > 0; o >>= 1) x += __shfl_xor(x, o, 64);
  return x;
}

__global__ __launch_bounds__(256) void k_softmax(float* __restrict__ wts) {
  const long row = blockIdx.x;
  const int qi = (int)(row & (Sn - 1));
  float* p = wts + row * Sn;
  const int tid = threadIdx.x, wv = tid >> 6, lane = tid & 63;
  const int j0 = tid * 8;
  float4 v0 = *(const float4*)(p + j0);
  float4 v1 = *(const float4*)(p + j0 + 4);
  float v[8] = {v0.x, v0.y, v0.z, v0.w, v1.x, v1.y, v1.z, v1.w};
  const float NI = -__builtin_inff();
#pragma unroll
  for (int t = 0; t < 8; ++t)
    if (j0 + t > qi) v[t] = NI;
  float mx = NI;
#pragma unroll
  for (int t = 0; t < 8; ++t) mx = fmaxf(mx, v[t]);
  mx = wred_max(mx);
  __shared__ float sm[4], ss[4];
  if (lane == 0) sm[wv] = mx;
  __syncthreads();
  mx = fmaxf(fmaxf(sm[0], sm[1]), fmaxf(sm[2], sm[3]));
  float s = 0.f;
#pragma unroll
  for (int t = 0; t < 8; ++t) {
    v[t] = __expf(v[t] - mx);
    s += v[t];
  }
  s = wred_sum(s);
  if (lane == 0) ss[wv] = s;
  __syncthreads();
  s = ss[0] + ss[1] + ss[2] + ss[3];
  const float inv = 1.f / s;
#pragma unroll
  for (int t = 0; t < 8; ++t) v[t] *= inv;
  *(float4*)(p + j0) = make_float4(v[0], v[1], v[2], v[3]);
  *(float4*)(p + j0 + 4) = make_float4(v[4], v[5], v[6], v[7]);
}

// ---------- PV: ctx[b,q,h*128+d] = sum_k W[bh][q][k] * vT[h*128+d][b*2048+k] ----------
__global__ __launch_bounds__(256) void k_pv(const float* __restrict__ wts,
                                            const bf16* __restrict__ vT,
                                            bf16* __restrict__ ctx) {
  const int it = blockIdx.x;
  const int bh = blockIdx.y, b = bh >> 4, h = bh & 15;
  const int tid = threadIdx.x, w = tid >> 6, lane = tid & 63;
  const int wm = (w >> 1) * 64, wn = (w & 1) * 64;
  const int lr = lane & 15, lg = lane >> 4;
  const float* Wb = wts + (long)bh * Sn * Sn;
  const bf16* Vb = vT + (long)h * DH * MROWS + (long)b * Sn;
  const int q0 = it * 128;
  const int kmax = q0 + 128;  // weights are exactly 0 beyond the causal boundary
  f32x4 acc[4][4] = {};
  for (int k = 0; k < kmax; k += 32) {
    const int kc = k + lg * 8;
    bf16x8 a[4], bb[4];
#pragma unroll
    for (int m = 0; m < 4; ++m) {
      const float* pw = Wb + (long)(q0 + wm + m * 16 + lr) * Sn + kc;
      float4 x0 = *(const float4*)pw;
      float4 x1 = *(const float4*)(pw + 4);
      bf16x8 t;
      t[0] = (bf16)x0.x; t[1] = (bf16)x0.y; t[2] = (bf16)x0.z; t[3] = (bf16)x0.w;
      t[4] = (bf16)x1.x; t[5] = (bf16)x1.y; t[6] = (bf16)x1.z; t[7] = (bf16)x1.w;
      a[m] = t;
    }
#pragma unroll
    for (int n = 0; n < 4; ++n)
      bb[n] = *(const bf16x8*)(Vb + (long)(wn + n * 16 + lr) * MROWS + kc);
#pragma unroll
    for (int m = 0; m < 4; ++m)
#pragma unroll
      for (int n = 0; n < 4; ++n) acc[m][n] = MFMA(a[m], bb[n], acc[m][n]);
  }
#pragma unroll
  for (int m = 0; m < 4; ++m)
#pragma unroll
    for (int n = 0; n < 4; ++n) {
      const int d = wn + n * 16 + lr;
#pragma unroll
      for (int r = 0; r < 4; ++r) {
        const int q = q0 + wm + m * 16 + lg * 4 + r;
        ctx[(long)(b * Sn + q) * Dn + h * DH + d] = (bf16)acc[m][n][r];
      }
    }
}

extern "C" void kernel_launch(void* const* d_in, const int* in_sizes, int n_in,
                              void* d_out, int out_size, void* d_ws, size_t ws_size,
                              hipStream_t stream) {
  const float* hid = (const float*)d_in[0];
  const float* wq = (const float*)d_in[1];
  const float* wk = (const float*)d_in[2];
  const float* wv = (const float*)d_in[3];
  const float* wo = (const float*)d_in[4];
  const float* bo = (const float*)d_in[5];
  float* out = (float*)d_out;
  float* wts = out + (long)Bc * Sn * Dn;  // attn_weights region: [64][2048][2048] fp32

  char* ws = (char*)d_ws;
  const long MB = 1 << 20;
  bf16* h_hi = (bf16*)(ws + 0 * MB);
  bf16* h_lo = (bf16*)(ws + 32 * MB);
  bf16* wq_hi = (bf16*)(ws + 64 * MB);
  bf16* wq_lo = (bf16*)(ws + 72 * MB);
  bf16* wk_hi = (bf16*)(ws + 80 * MB);
  bf16* wk_lo = (bf16*)(ws + 88 * MB);
  bf16* wv_bf = (bf16*)(ws + 96 * MB);
  bf16* wo_bf = (bf16*)(ws + 104 * MB);
  bf16* q_hi = (bf16*)(ws + 112 * MB);
  bf16* q_lo = (bf16*)(ws + 144 * MB);
  bf16* k_hi = (bf16*)(ws + 176 * MB);
  bf16* k_lo = (bf16*)(ws + 208 * MB);
  bf16* vT = (bf16*)(ws + 240 * MB);
  bf16* ctx = (bf16*)(ws + 272 * MB);

  const long nH = (long)Bc * Sn * Dn;  // 16,777,216
  const long nW = (long)Dn * Dn;       // 4,194,304

  k_split<<<nH / 1024, 256, 0, stream>>>(hid, h_hi, h_lo, nH);
  k_split<<<nW / 1024, 256, 0, stream>>>(wq, wq_hi, wq_lo, nW);
  k_split<<<nW / 1024, 256, 0, stream>>>(wk, wk_hi, wk_lo, nW);
  k_cvt<<<nW / 1024, 256, 0, stream>>>(wv, wv_bf, nW);
  k_cvt<<<nW / 1024, 256, 0, stream>>>(wo, wo_bf, nW);

  // q = hid @ wq^T, k = hid @ wk^T   [8192 x 2048], split-bf16 outputs
  k_gemm_bt<3, 0, false><<<dim3(16, 64), 256, 0, stream>>>(
      h_hi, h_lo, Dn, wq_hi, wq_lo, Dn, Dn, q_hi, q_lo, nullptr, nullptr, Dn);
  k_gemm_bt<3, 0, false><<<dim3(16, 64), 256, 0, stream>>>(
      h_hi, h_lo, Dn, wk_hi, wk_lo, Dn, Dn, k_hi, k_lo, nullptr, nullptr, Dn);
  // vT = wv @ hid^T   [2048 x 8192] bf16 (v pre-transposed for PV's B operand)
  k_gemm_bt<1, 1, false><<<dim3(64, 16), 256, 0, stream>>>(
      wv_bf, nullptr, Dn, h_hi, nullptr, Dn, Dn, vT, nullptr, nullptr, nullptr, MROWS);
  // raw scores (lower-triangular tiles) straight into the attn_weights output region
  k_gemm_bt<3, 3, true><<<dim3(16, 16, 64), 256, 0, stream>>>(
      q_hi, q_lo, Dn, k_hi, k_lo, Dn, DH, nullptr, nullptr, wts, nullptr, Sn);
  // in-place causal softmax (writes exact zeros above the diagonal)
  k_softmax<<<64 * Sn, 256, 0, stream>>>(wts);
  // ctx = W @ v  (bf16 out, [B,S,D] layout)
  k_pv<<<dim3(16, 64), 256, 0, stream>>>(wts, vT, ctx);
  // out = ctx @ wo^T + bo
  k_gemm_bt<1, 2, false><<<dim3(16, 64), 256, 0, stream>>>(
      ctx, nullptr, Dn, wo_bf, nullptr, Dn, Dn, nullptr, nullptr, out, bo, Dn);
}